// Round 1
// baseline (654.089 us; speedup 1.0000x reference)
//
#include <hip/hip_runtime.h>
#include <math.h>

#define NPTS 400000
#define K27  27

typedef unsigned short u16;
typedef __bf16 bf16x8 __attribute__((ext_vector_type(8)));
typedef float  f32x4  __attribute__((ext_vector_type(4)));

__device__ __forceinline__ u16 f2bf(float f) {
    unsigned u = __float_as_uint(f);
    u += 0x7FFFu + ((u >> 16) & 1u);   // RNE round to bf16
    return (u16)(u >> 16);
}
__device__ __forceinline__ unsigned pack2(float lo, float hi) {
    return (unsigned)f2bf(lo) | ((unsigned)f2bf(hi) << 16);
}
__device__ __forceinline__ bf16x8 pack8(float4 x, float4 y) {
    union { uint4 u; bf16x8 v; } r;
    r.u.x = pack2(x.x, x.y); r.u.y = pack2(x.z, x.w);
    r.u.z = pack2(y.x, y.y); r.u.w = pack2(y.z, y.w);
    return r.v;
}
__device__ __forceinline__ bf16x8 zero8() {
    union { uint4 u; bf16x8 v; } r;
    r.u.x = 0; r.u.y = 0; r.u.z = 0; r.u.w = 0;
    return r.v;
}

// ---------------------------------------------------------------------------
// prep: transpose+pad W1 [27][64][38] -> W1t [27][48][64] bf16 (n-major, k-contig)
//       and W2 [27][38][38] -> W2t [27][48][64] bf16, zero-padded.
// Also zeroes the padding row (index NPTS) of h and Fb so the gather path
// needs no branch: idx==NPTS reads a zero row.
// ---------------------------------------------------------------------------
__global__ void prep_w(const float* __restrict__ W1, const float* __restrict__ W2,
                       u16* __restrict__ W1t, u16* __restrict__ W2t,
                       u16* __restrict__ hpad, u16* __restrict__ fpad)
{
    int i = blockIdx.x * 256 + threadIdx.x;
    if (i < 64) {                 // one 64-short row each
        hpad[i] = 0;
        if (fpad) fpad[i] = 0;
    }
    const int TOT = K27 * 48 * 64;
    if (i >= TOT) return;
    int k  = i / (48 * 64);
    int r  = i % (48 * 64);
    int n  = r >> 6;    // 0..47 (out channel)
    int kc = r & 63;    // 0..63 (in channel)
    u16 w1 = 0, w2 = 0;
    if (n < 38) {
        w1 = f2bf(W1[(k * 64 + kc) * 38 + n]);
        if (kc < 38) w2 = f2bf(W2[(k * 38 + kc) * 38 + n]);
    }
    W1t[i] = w1;
    W2t[i] = w2;
}

// ---------------------------------------------------------------------------
// prep: features fp32 [N][64] -> bf16 [N][64]  (8 elems / thread)
// ---------------------------------------------------------------------------
__global__ void prep_feat(const float* __restrict__ F, u16* __restrict__ Fb)
{
    size_t i = (size_t)blockIdx.x * 256 + threadIdx.x;
    const size_t TOT = (size_t)NPTS * 64 / 8;              // 3,200,000 exact
    if (i >= TOT) return;
    const float4* fp = (const float4*)(F + i * 8);
    float4 a = fp[0], b = fp[1];
    uint4 v;
    v.x = pack2(a.x, a.y); v.y = pack2(a.z, a.w);
    v.z = pack2(b.x, b.y); v.w = pack2(b.z, b.w);
    *(uint4*)(Fb + i * 8) = v;
}

// ---------------------------------------------------------------------------
// gather-GEMM layer, LDS-free / barrier-free.
// Block = 128 threads (2 waves); each wave owns 64 rows (4 row-tiles of 16).
// MFMA fragments are loaded DIRECTLY from global:
//   A-frag(rt,ks): 16B at  in + idx[rt*16+l16]*64 + ks*32 + quad*8   (gather)
//   B-frag(nt,ks): 16B at  Wt + k*3072 + (nt*16+l16)*64 + ks*32 + quad*8 (L1-hot)
// Next k's neighbor indices are prefetched during the current k's MFMAs.
// LAYER==1: -> GELU -> h bf16 [N+1][64] (cols 48..63 zeroed)
// LAYER==2: -> fp32 out [N][38]
// ---------------------------------------------------------------------------
template<int LAYER, bool BF16IN>
__global__ __launch_bounds__(128)
void spconv(const void* __restrict__ in_, const int* __restrict__ nbr,
            const u16* __restrict__ Wt, void* __restrict__ out_)
{
    const int t     = threadIdx.x;
    const int wave  = t >> 6;
    const int lane  = t & 63;
    const int quad  = lane >> 4;
    const int l16   = lane & 15;
    const int rbase = blockIdx.x * 128 + wave * 64;   // wave's first row; 3125*128==400000

    f32x4 acc[4][3] = {};

    int idx[4];
    #pragma unroll
    for (int rt = 0; rt < 4; ++rt)
        idx[rt] = nbr[rbase + rt * 16 + l16];         // k = 0

    const u16* wk = Wt + (size_t)(l16 * 64 + quad * 8);   // per-lane W base, k=0

    for (int k = 0; k < K27; ++k) {
        // ---- A fragments: direct gather, 8 x 16B per lane ----
        bf16x8 a[4][2];
        if (BF16IN) {
            const u16* F = (const u16*)in_;
            #pragma unroll
            for (int rt = 0; rt < 4; ++rt) {
                const u16* rowp = F + (size_t)idx[rt] * 64 + quad * 8;
                a[rt][0] = *(const bf16x8*)(rowp);
                a[rt][1] = *(const bf16x8*)(rowp + 32);
            }
        } else {
            const float* F = (const float*)in_;
            #pragma unroll
            for (int rt = 0; rt < 4; ++rt) {
                if (idx[rt] < NPTS) {
                    const float* rowp = F + (size_t)idx[rt] * 64 + quad * 8;
                    float4 f0 = *(const float4*)(rowp);
                    float4 f1 = *(const float4*)(rowp + 4);
                    float4 f2 = *(const float4*)(rowp + 32);
                    float4 f3 = *(const float4*)(rowp + 36);
                    a[rt][0] = pack8(f0, f1);
                    a[rt][1] = pack8(f2, f3);
                } else {
                    a[rt][0] = zero8();
                    a[rt][1] = zero8();
                }
            }
        }
        // ---- B fragments: 6 x 16B per lane, same 6KB for every wave -> L1 ----
        bf16x8 b[3][2];
        #pragma unroll
        for (int nt = 0; nt < 3; ++nt) {
            b[nt][0] = *(const bf16x8*)(wk + nt * 1024);
            b[nt][1] = *(const bf16x8*)(wk + nt * 1024 + 32);
        }
        // ---- prefetch next k's indices (hidden under the MFMAs below) ----
        int idxn[4];
        const bool more = (k + 1 < K27);
        if (more) {
            const int* nrow = nbr + (size_t)(k + 1) * NPTS + rbase;
            #pragma unroll
            for (int rt = 0; rt < 4; ++rt) idxn[rt] = nrow[rt * 16 + l16];
        }
        // ---- 24 MFMAs, b-frags reused across 4 row-tiles ----
        #pragma unroll
        for (int ks = 0; ks < 2; ++ks)
            #pragma unroll
            for (int rt = 0; rt < 4; ++rt)
                #pragma unroll
                for (int nt = 0; nt < 3; ++nt)
                    acc[rt][nt] = __builtin_amdgcn_mfma_f32_16x16x32_bf16(
                        a[rt][ks], b[nt][ks], acc[rt][nt], 0, 0, 0);
        if (more) {
            #pragma unroll
            for (int rt = 0; rt < 4; ++rt) idx[rt] = idxn[rt];
        }
        wk += 48 * 64;
    }

    // ---- epilogue (C layout: col = l16, row = quad*4 + r) ----
    if (LAYER == 1) {
        u16* h = (u16*)out_;
        #pragma unroll
        for (int rt = 0; rt < 4; ++rt) {
            #pragma unroll
            for (int r = 0; r < 4; ++r) {
                size_t ro = (size_t)(rbase + rt * 16 + quad * 4 + r) * 64;
                #pragma unroll
                for (int nt = 0; nt < 3; ++nt) {
                    float x = acc[rt][nt][r];
                    float g = 0.5f * x * (1.0f + erff(x * 0.70710678118654752f));
                    h[ro + nt * 16 + l16] = f2bf(g);
                }
                h[ro + 48 + l16] = 0;      // zero pad cols 48..63
            }
        }
    } else {
        float* out = (float*)out_;
        #pragma unroll
        for (int rt = 0; rt < 4; ++rt) {
            #pragma unroll
            for (int nt = 0; nt < 3; ++nt) {
                int col = nt * 16 + l16;
                if (col < 38) {
                    #pragma unroll
                    for (int r = 0; r < 4; ++r) {
                        int row = rbase + rt * 16 + quad * 4 + r;
                        out[(size_t)row * 38 + col] = acc[rt][nt][r];
                    }
                }
            }
        }
    }
}

// ---------------------------------------------------------------------------
extern "C" void kernel_launch(void* const* d_in, const int* in_sizes, int n_in,
                              void* d_out, int out_size, void* d_ws, size_t ws_size,
                              hipStream_t stream)
{
    const float* feat = (const float*)d_in[0];   // [N][64] fp32
    const int*   nbr  = (const int*)  d_in[1];   // [27][N] int32, N == pad idx
    const float* W1   = (const float*)d_in[2];   // [27][64][38]
    const float* W2   = (const float*)d_in[3];   // [27][38][38]

    const size_t hbytes = (size_t)(NPTS + 1) * 64 * 2;   // h incl. zero pad row
    const size_t wbytes = (size_t)K27 * 48 * 64 * 2;     // 165,888

    char* ws  = (char*)d_ws;
    u16* h    = (u16*)ws;
    u16* W1t  = (u16*)(ws + hbytes);
    u16* W2t  = (u16*)(ws + hbytes + wbytes);
    u16* Fb   = (u16*)(ws + hbytes + 2 * wbytes);
    const bool full = ws_size >= hbytes * 2 + 2 * wbytes;   // bf16 feature copy fits?

    prep_w<<<(K27 * 48 * 64 + 255) / 256, 256, 0, stream>>>(
        W1, W2, W1t, W2t,
        h + (size_t)NPTS * 64,
        full ? Fb + (size_t)NPTS * 64 : (u16*)nullptr);

    const int nblk = NPTS / 128;   // 3125, exact
    if (full) {
        prep_feat<<<(int)(((size_t)NPTS * 64 / 8 + 255) / 256), 256, 0, stream>>>(feat, Fb);
        spconv<1, true ><<<nblk, 128, 0, stream>>>(Fb,   nbr, W1t, h);
    } else {
        spconv<1, false><<<nblk, 128, 0, stream>>>(feat, nbr, W1t, h);
    }
    spconv<2, true ><<<nblk, 128, 0, stream>>>(h, nbr, W2t, d_out);
}